// Round 1
// baseline (12457.171 us; speedup 1.0000x reference)
//
#include <hip/hip_runtime.h>

// ---------------- problem constants ----------------
#define BB_ 32      // batch
#define SS_ 256     // src len
#define TT_ 64      // tgt len
#define TD_ 63      // decoder steps
#define EE_ 128     // embed
#define HH_ 256     // enc hidden per dir
#define H2_ 512     // dec hidden
#define VV_ 32000

__device__ __forceinline__ float sigf(float x){ return 1.0f/(1.0f+__expf(-x)); }
__device__ __forceinline__ float tanhf_fast(float x){ return 1.0f - 2.0f/(__expf(2.0f*x)+1.0f); }

// ---------------- d_out scratch layout (float offsets) ----------------
// everything here is dead before the final logits GEMM overwrites d_out
#define OFF_Z        0u           // 8192 x 2048
#define OFF_Y0       16777216u    // 8192 x 512
#define OFF_Y1       20971520u    // 8192 x 512
#define OFF_ZPRE     25165824u    // 2016 x 2048
#define OFF_H1ALL    29294592u    // 2016 x 512
#define OFF_SRCE     30326784u    // 8192 x 128
#define OFF_TGTE     31375360u    // 2016 x 128
#define OFF_EPROJ    31633408u    // 8192 x 256
#define OFF_ET0      33730560u    // 2 x 64 x 1024 x 4  (enc Whh l0 transposed)
#define OFF_ET1      34254848u
#define OFF_DTIH0    34779136u    // 128 x 2048 x 4
#define OFF_DTHH0    35827712u
#define OFF_DTIH1    36876288u
#define OFF_DTHH1    37924864u
#define OFF_AT       38973440u    // 128 x 256 x 4 (W1_dec transposed)
#define OFF_STATES   39104512u    // 12 x 16384 zeroed below
#define OFF_E0H0     39104512u
#define OFF_E0H1     39120896u
#define OFF_E0C      39137280u
#define OFF_E1H0     39153664u
#define OFF_E1H1     39170048u
#define OFF_E1C      39186432u
#define OFF_DH0A     39202816u
#define OFF_DH0B     39219200u
#define OFF_DC0      39235584u
#define OFF_DH1A     39251968u
#define OFF_DH1B     39268352u
#define OFF_DC1      39284736u
#define OFF_Q        39301120u    // 32 x 256
#define OFF_SC       39309312u    // 32 x 256
#define OFF_CTXP     39317504u    // 4 x 32 x 512
#define N_STATES     196608u

// ---------------- utility kernels ----------------
__global__ void k_zero(float* __restrict__ p, int n){
  int i = blockIdx.x*256 + threadIdx.x;
  if (i < n) p[i] = 0.f;
}

// gather embeddings: src_e[(s*32+b)][e], tgt_e[(t*32+b)][e] (t<63)
__global__ void k_gather(const int* __restrict__ src, const int* __restrict__ tgt,
                         const float* __restrict__ emb,
                         float* __restrict__ src_e, float* __restrict__ tgt_e){
  int idx = blockIdx.x*256 + threadIdx.x;
  const int total = (8192 + 2016) * 32;          // rows * (128/4)
  if (idx >= total) return;
  int row = idx >> 5, j = idx & 31;
  int tok; float* dst;
  if (row < 8192){
    int s = row >> 5, b = row & 31;
    tok = src[b*SS_ + s];
    dst = src_e + (size_t)row*EE_;
  } else {
    int r2 = row - 8192;
    int t = r2 >> 5, b = r2 & 31;
    tok = tgt[b*TT_ + t];
    dst = tgt_e + (size_t)r2*EE_;
  }
  float4 v = *(const float4*)(emb + (size_t)tok*EE_ + j*4);
  *(float4*)(dst + j*4) = v;
}

// transpose W (C rows x Kd cols, row stride ldb, col offset off) into
// WT[(k/4)*C + c]*4 + (k%4)  (k-major float4 interleave)
__global__ __launch_bounds__(256) void k_transpose(
    const float* __restrict__ src, float* __restrict__ dst,
    int C, int Kd, int ldb, int off){
  __shared__ float tile[64][68];
  int c0 = blockIdx.x*64, k0 = blockIdx.y*64;
  int tid = threadIdx.x;
  for (int idx = tid; idx < 1024; idx += 256){
    int r = idx >> 4, j4 = idx & 15;
    float4 v = *(const float4*)(src + (size_t)(c0+r)*ldb + off + k0 + j4*4);
    tile[r][j4*4+0]=v.x; tile[r][j4*4+1]=v.y; tile[r][j4*4+2]=v.z; tile[r][j4*4+3]=v.w;
  }
  __syncthreads();
  for (int idx = tid; idx < 1024; idx += 256){
    int k4l = idx >> 6, cl = idx & 63;
    float4 v = make_float4(tile[cl][k4l*4+0], tile[cl][k4l*4+1],
                           tile[cl][k4l*4+2], tile[cl][k4l*4+3]);
    *(float4*)(dst + ((size_t)(k0/4 + k4l)*C + c0 + cl)*4) = v;
  }
}

// ---------------- generic tiled f32 GEMM: C = A(MxK) @ B(NxK)^T + bias ----------------
// flags: 1 = relu, 2 = remap rows (t*32+b) -> out[(b*63+t)*V + n]
__global__ __launch_bounds__(256) void k_gemm(
    const float* __restrict__ A, const float* __restrict__ Bm,
    const float* __restrict__ bias, float* __restrict__ C,
    int M, int N, int K, int ldb, int flags){
  __shared__ float As[16][132];
  __shared__ float Bs[16][132];
  int tid = threadIdx.x;
  int m0 = blockIdx.x * 128;
  int n0 = blockIdx.y * 128;
  int tx = tid & 15, ty = tid >> 4;
  float acc[8][8];
  #pragma unroll
  for (int i=0;i<8;i++)
    #pragma unroll
    for (int j=0;j<8;j++) acc[i][j]=0.f;

  for (int k0 = 0; k0 < K; k0 += 16){
    #pragma unroll
    for (int L=0; L<2; L++){
      int idx = tid + L*256;
      int row = idx >> 2, k4 = idx & 3;
      float4 v = make_float4(0.f,0.f,0.f,0.f);
      if (m0+row < M) v = *(const float4*)(A + (size_t)(m0+row)*K + k0 + k4*4);
      As[k4*4+0][row]=v.x; As[k4*4+1][row]=v.y; As[k4*4+2][row]=v.z; As[k4*4+3][row]=v.w;
      float4 w = *(const float4*)(Bm + (size_t)(n0+row)*ldb + k0 + k4*4);
      Bs[k4*4+0][row]=w.x; Bs[k4*4+1][row]=w.y; Bs[k4*4+2][row]=w.z; Bs[k4*4+3][row]=w.w;
    }
    __syncthreads();
    #pragma unroll
    for (int kk=0; kk<16; kk++){
      float4 a0 = *(const float4*)&As[kk][ty*8];
      float4 a1 = *(const float4*)&As[kk][ty*8+4];
      float4 b0 = *(const float4*)&Bs[kk][tx*8];
      float4 b1 = *(const float4*)&Bs[kk][tx*8+4];
      float av[8] = {a0.x,a0.y,a0.z,a0.w,a1.x,a1.y,a1.z,a1.w};
      float bv[8] = {b0.x,b0.y,b0.z,b0.w,b1.x,b1.y,b1.z,b1.w};
      #pragma unroll
      for (int i=0;i<8;i++)
        #pragma unroll
        for (int j=0;j<8;j++) acc[i][j] += av[i]*bv[j];
    }
    __syncthreads();
  }
  #pragma unroll
  for (int i=0;i<8;i++){
    int m = m0 + ty*8 + i;
    if (m >= M) continue;
    #pragma unroll
    for (int j=0;j<8;j++){
      int n = n0 + tx*8 + j;
      float v = acc[i][j] + bias[n];
      if (flags & 1) v = fmaxf(v, 0.f);
      if (flags & 2) C[(size_t)((m & 31)*63 + (m >> 5))*VV_ + n] = v;
      else           C[(size_t)m*N + n] = v;
    }
  }
}

// ---------------- encoder recurrent step ----------------
// grid (16 unit-slices, 4 batch-groups, 2 dirs), block 256
// WT: per-dir k-major transposed Whh: [(d)*65536 + k4*1024 + col] float4
__global__ __launch_bounds__(256) void k_enc_step(
    const float* __restrict__ Z, const float* __restrict__ WT,
    const float* __restrict__ h_in, float* __restrict__ h_out,
    float* __restrict__ c, float* __restrict__ y, int i){
  int cs = blockIdx.x, bg = blockIdx.y, d = blockIdx.z;
  int t = d ? (SS_-1-i) : i;
  __shared__ float hs[8][256];
  __shared__ float zsl[4][16][8];
  int tid = threadIdx.x;
  for (int idx = tid; idx < 2048; idx += 256){
    int bb = idx >> 8, k = idx & 255;
    hs[bb][k] = h_in[((size_t)d*BB_ + bg*8+bb)*HH_ + k];
  }
  __syncthreads();
  int bb = tid >> 5, cl = tid & 31;
  int g0 = cl >> 4, ul = cl & 15;
  int col0 = g0*256 + cs*16 + ul;
  int col1 = (g0+2)*256 + cs*16 + ul;
  const float4* wt = (const float4*)WT + (size_t)d*65536;
  const float4* h4 = (const float4*)hs[bb];
  float a0=0.f, a1=0.f;
  #pragma unroll 8
  for (int k4=0; k4<64; k4++){
    float4 hv = h4[k4];
    float4 wa = wt[(size_t)k4*1024 + col0];
    float4 wb = wt[(size_t)k4*1024 + col1];
    a0 += wa.x*hv.x + wa.y*hv.y + wa.z*hv.z + wa.w*hv.w;
    a1 += wb.x*hv.x + wb.y*hv.y + wb.z*hv.z + wb.w*hv.w;
  }
  const float* zr = Z + ((size_t)t*BB_ + bg*8+bb)*2048 + d*1024;
  zsl[g0][ul][bb]   = zr[col0] + a0;
  zsl[g0+2][ul][bb] = zr[col1] + a1;
  __syncthreads();
  if (tid < 128){
    int u_l = tid & 15, b2 = tid >> 4;
    float zi = zsl[0][u_l][b2], zf = zsl[1][u_l][b2];
    float zg = zsl[2][u_l][b2], zo = zsl[3][u_l][b2];
    size_t ci = ((size_t)d*BB_ + bg*8+b2)*HH_ + cs*16 + u_l;
    float cn = sigf(zf)*c[ci] + sigf(zi)*tanhf_fast(zg);
    float hn = sigf(zo)*tanhf_fast(cn);
    c[ci] = cn; h_out[ci] = hn;
    y[((size_t)t*BB_ + bg*8+b2)*512 + d*256 + cs*16 + u_l] = hn;
  }
}

// ---------------- decoder LSTM step (shared by cell0/cell1) ----------------
// grid (64 unit-slices of 8, 4 batch-groups), block 256, 1 z-col per thread
__global__ __launch_bounds__(256) void k_lstm(
    const float* __restrict__ in1, int in1_is_ctxp,
    const float* __restrict__ zsrc, int z_is_bias,
    const float* __restrict__ W1T, const float* __restrict__ W2T,
    const float* __restrict__ h_in, float* __restrict__ c,
    float* __restrict__ h_out, float* __restrict__ H1all, int t){
  int cs = blockIdx.x, bg = blockIdx.y, tid = threadIdx.x;
  __shared__ float s1[8][512];
  __shared__ float s2[8][512];
  __shared__ float zsl[4][8][8];
  for (int idx = tid; idx < 4096; idx += 256){
    int bb = idx >> 9, k = idx & 511;
    int b = bg*8 + bb;
    float v;
    if (in1_is_ctxp)
      v = in1[(size_t)b*512+k] + in1[(size_t)(32+b)*512+k]
        + in1[(size_t)(64+b)*512+k] + in1[(size_t)(96+b)*512+k];
    else v = in1[(size_t)b*512+k];
    s1[bb][k] = v;
    s2[bb][k] = h_in[(size_t)b*512+k];
  }
  __syncthreads();
  int bb = tid >> 5, cl = tid & 31;
  int gate = cl >> 3, ul = cl & 7;
  int col = gate*512 + cs*8 + ul;
  const float4* w1 = (const float4*)W1T;
  const float4* w2 = (const float4*)W2T;
  const float4* p1 = (const float4*)s1[bb];
  const float4* p2 = (const float4*)s2[bb];
  float a = 0.f;
  #pragma unroll 4
  for (int k4=0; k4<128; k4++){
    float4 x = p1[k4], h = p2[k4];
    float4 wa = w1[(size_t)k4*2048 + col];
    float4 va = w2[(size_t)k4*2048 + col];
    a += wa.x*x.x + wa.y*x.y + wa.z*x.z + wa.w*x.w
       + va.x*h.x + va.y*h.y + va.z*h.z + va.w*h.w;
  }
  int b = bg*8 + bb;
  float z0 = z_is_bias ? zsrc[col] : zsrc[((size_t)t*BB_ + b)*2048 + col];
  zsl[gate][ul][bb] = z0 + a;
  __syncthreads();
  if (tid < 64){
    int u_l = tid & 7, b2 = tid >> 3;
    float zi = zsl[0][u_l][b2], zf = zsl[1][u_l][b2];
    float zg = zsl[2][u_l][b2], zo = zsl[3][u_l][b2];
    int bq = bg*8 + b2; int u = cs*8 + u_l;
    size_t ci = (size_t)bq*512 + u;
    float cn = sigf(zf)*c[ci] + sigf(zi)*tanhf_fast(zg);
    float hn = sigf(zo)*tanhf_fast(cn);
    c[ci] = cn; h_out[ci] = hn;
    if (H1all) H1all[((size_t)t*BB_ + bq)*512 + u] = hn;
  }
}

// ---------------- attention kernels ----------------
// q = h1 @ W1_dec^T : grid (4 col-slices of 64, 4 batch-groups), block 256
__global__ __launch_bounds__(256) void k_q(
    const float* __restrict__ aT, const float* __restrict__ h1, float* __restrict__ q){
  int sl = blockIdx.x, bg = blockIdx.y, tid = threadIdx.x;
  __shared__ float hs[8][512];
  for (int idx = tid; idx < 4096; idx += 256){
    int bb = idx >> 9, k = idx & 511;
    hs[bb][k] = h1[(size_t)(bg*8+bb)*512 + k];
  }
  __syncthreads();
  int bb = tid >> 5, cl = tid & 31;
  int c0 = sl*64 + cl, c1 = sl*64 + cl + 32;
  const float4* w = (const float4*)aT;
  const float4* hh = (const float4*)hs[bb];
  float a0=0.f, a1=0.f;
  #pragma unroll 4
  for (int k4=0; k4<128; k4++){
    float4 hv = hh[k4];
    float4 wa = w[(size_t)k4*256 + c0];
    float4 wb = w[(size_t)k4*256 + c1];
    a0 += wa.x*hv.x + wa.y*hv.y + wa.z*hv.z + wa.w*hv.w;
    a1 += wb.x*hv.x + wb.y*hv.y + wb.z*hv.z + wb.w*hv.w;
  }
  q[(size_t)(bg*8+bb)*256 + c0] = a0;
  q[(size_t)(bg*8+bb)*256 + c1] = a1;
}

// scores[b][s] = sum_h tanh(encproj[s,b,h] + q[b,h]) * w2[h] + b2
// grid (32 b, 8 s-slices of 32), block 256 (32 s x 8 h-chunks)
__global__ __launch_bounds__(256) void k_scores(
    const float* __restrict__ encproj, const float* __restrict__ q,
    const float* __restrict__ w2, const float* __restrict__ b2,
    float* __restrict__ scores){
  int b = blockIdx.x, ss = blockIdx.y, tid = threadIdx.x;
  __shared__ float qs[256], w2s[256], ps[32][8];
  qs[tid] = q[(size_t)b*256 + tid];
  w2s[tid] = w2[tid];
  __syncthreads();
  int sl = tid >> 3, hc = tid & 7;
  int s = ss*32 + sl;
  const float4* ep = (const float4*)(encproj + ((size_t)s*BB_ + b)*256 + hc*32);
  const float4* q4 = (const float4*)(qs + hc*32);
  const float4* w4 = (const float4*)(w2s + hc*32);
  float acc = 0.f;
  #pragma unroll
  for (int k=0;k<8;k++){
    float4 e = ep[k], qq = q4[k], ww = w4[k];
    acc += tanhf_fast(e.x+qq.x)*ww.x + tanhf_fast(e.y+qq.y)*ww.y
         + tanhf_fast(e.z+qq.z)*ww.z + tanhf_fast(e.w+qq.w)*ww.w;
  }
  ps[sl][hc] = acc;
  __syncthreads();
  if (hc == 0){
    float r = 0.f;
    #pragma unroll
    for (int j=0;j<8;j++) r += ps[sl][j];
    scores[(size_t)b*256 + s] = r + b2[0];
  }
}

// softmax over s + partial context: grid (32 b, 4 s-chunks of 64), block 256
__global__ __launch_bounds__(256) void k_sm_ctx(
    const float* __restrict__ scores, const float* __restrict__ enc_out,
    float* __restrict__ ctxp){
  int b = blockIdx.x, ch = blockIdx.y, tid = threadIdx.x;
  __shared__ float es[256];
  __shared__ float red[256];
  float sc = scores[(size_t)b*256 + tid];
  red[tid] = sc; __syncthreads();
  for (int off=128; off; off >>= 1){
    if (tid < off) red[tid] = fmaxf(red[tid], red[tid+off]);
    __syncthreads();
  }
  float mx = red[0]; __syncthreads();
  float e = __expf(sc - mx);
  es[tid] = e; red[tid] = e; __syncthreads();
  for (int off=128; off; off >>= 1){
    if (tid < off) red[tid] += red[tid+off];
    __syncthreads();
  }
  float inv = 1.0f / red[0];
  float p0=0.f, p1=0.f;
  for (int sscan=0; sscan<64; sscan++){
    int s = ch*64 + sscan;
    float a = es[s] * inv;
    const float* eo = enc_out + ((size_t)s*BB_ + b)*512;
    p0 += a * eo[tid];
    p1 += a * eo[tid+256];
  }
  ctxp[((size_t)ch*BB_ + b)*512 + tid]       = p0;
  ctxp[((size_t)ch*BB_ + b)*512 + tid + 256] = p1;
}

// decoder init: h0/c0 from enc layer0 finals, h1/c1 from layer1 finals
__global__ void k_dec_init(
    const float* __restrict__ eh0, const float* __restrict__ ec0,
    const float* __restrict__ eh1, const float* __restrict__ ec1,
    float* __restrict__ h0, float* __restrict__ c0,
    float* __restrict__ h1, float* __restrict__ c1){
  int idx = blockIdx.x*256 + threadIdx.x;
  if (idx >= BB_*512) return;
  int b = idx >> 9, u = idx & 511;
  int d = u >> 8, uu = u & 255;
  size_t s = ((size_t)d*BB_ + b)*256 + uu;
  h0[idx] = eh0[s]; c0[idx] = ec0[s];
  h1[idx] = eh1[s]; c1[idx] = ec1[s];
}

// ---------------- host launch ----------------
extern "C" void kernel_launch(void* const* d_in, const int* in_sizes, int n_in,
                              void* d_out, int out_size, void* d_ws, size_t ws_size,
                              hipStream_t stream){
  (void)in_sizes; (void)n_in; (void)out_size; (void)ws_size;
  const int*   src   = (const int*)d_in[0];
  const int*   tgt   = (const int*)d_in[1];
  const float* emb   = (const float*)d_in[2];
  const float* eWih0 = (const float*)d_in[3];
  const float* eWhh0 = (const float*)d_in[4];
  const float* eb0   = (const float*)d_in[5];
  const float* eWih1 = (const float*)d_in[6];
  const float* eWhh1 = (const float*)d_in[7];
  const float* eb1   = (const float*)d_in[8];
  const float* dWih0 = (const float*)d_in[9];
  const float* dWhh0 = (const float*)d_in[10];
  const float* db0   = (const float*)d_in[11];
  const float* dWih1 = (const float*)d_in[12];
  const float* dWhh1 = (const float*)d_in[13];
  const float* db1   = (const float*)d_in[14];
  const float* aW1   = (const float*)d_in[15];
  const float* ab1   = (const float*)d_in[16];
  const float* aW2   = (const float*)d_in[17];
  const float* ab2   = (const float*)d_in[18];
  const float* oW1   = (const float*)d_in[19];
  const float* ob1   = (const float*)d_in[20];
  const float* oW2   = (const float*)d_in[21];
  const float* ob2   = (const float*)d_in[22];

  float* F = (float*)d_out;
  float* Z     = F + OFF_Z;
  float* y0    = F + OFF_Y0;
  float* y1    = F + OFF_Y1;
  float* zpre  = F + OFF_ZPRE;
  float* H1    = F + OFF_H1ALL;
  float* srcE  = F + OFF_SRCE;
  float* tgtE  = F + OFF_TGTE;
  float* eproj = F + OFF_EPROJ;
  float* eT0   = F + OFF_ET0;
  float* eT1   = F + OFF_ET1;
  float* dTih0 = F + OFF_DTIH0;
  float* dThh0 = F + OFF_DTHH0;
  float* dTih1 = F + OFF_DTIH1;
  float* dThh1 = F + OFF_DTHH1;
  float* aT    = F + OFF_AT;
  float* e0h[2] = { F + OFF_E0H0, F + OFF_E0H1 };
  float* e0c    = F + OFF_E0C;
  float* e1h[2] = { F + OFF_E1H0, F + OFF_E1H1 };
  float* e1c    = F + OFF_E1C;
  float* dh0[2] = { F + OFF_DH0A, F + OFF_DH0B };
  float* dc0    = F + OFF_DC0;
  float* dh1[2] = { F + OFF_DH1A, F + OFF_DH1B };
  float* dc1    = F + OFF_DC1;
  float* q      = F + OFF_Q;
  float* sc     = F + OFF_SC;
  float* ctxp   = F + OFF_CTXP;
  float* hid    = (float*)d_ws;   // 2016 x 256 (2MB) — only ws usage

  // weight transposes (k-major, float4-interleaved)
  k_transpose<<<dim3(16,4),256,0,stream>>>(eWhh0,            eT0,          1024,256,256,0);
  k_transpose<<<dim3(16,4),256,0,stream>>>(eWhh0+1024*256,   eT0+262144,   1024,256,256,0);
  k_transpose<<<dim3(16,4),256,0,stream>>>(eWhh1,            eT1,          1024,256,256,0);
  k_transpose<<<dim3(16,4),256,0,stream>>>(eWhh1+1024*256,   eT1+262144,   1024,256,256,0);
  k_transpose<<<dim3(32,8),256,0,stream>>>(dWih0,            dTih0,        2048,512,640,128);
  k_transpose<<<dim3(32,8),256,0,stream>>>(dWhh0,            dThh0,        2048,512,512,0);
  k_transpose<<<dim3(32,8),256,0,stream>>>(dWih1,            dTih1,        2048,512,512,0);
  k_transpose<<<dim3(32,8),256,0,stream>>>(dWhh1,            dThh1,        2048,512,512,0);
  k_transpose<<<dim3(4,8),256,0,stream>>>(aW1,               aT,           256,512,1024,0);

  k_zero<<<(N_STATES+255)/256,256,0,stream>>>(F + OFF_STATES, N_STATES);
  k_gather<<<((8192+2016)*32+255)/256,256,0,stream>>>(src, tgt, emb, srcE, tgtE);

  // encoder layer0 input projection (both dirs stacked: N=2048)
  k_gemm<<<dim3(64,16),256,0,stream>>>(srcE, eWih0, eb0, Z, 8192,2048,128,128,0);
  for (int i=0;i<SS_;i++)
    k_enc_step<<<dim3(16,4,2),256,0,stream>>>(Z, eT0, e0h[i&1], e0h[1-(i&1)], e0c, y0, i);

  // encoder layer1
  k_gemm<<<dim3(64,16),256,0,stream>>>(y0, eWih1, eb1, Z, 8192,2048,512,512,0);
  for (int i=0;i<SS_;i++)
    k_enc_step<<<dim3(16,4,2),256,0,stream>>>(Z, eT1, e1h[i&1], e1h[1-(i&1)], e1c, y1, i);

  // enc_proj = enc_out @ W1_enc^T + b1   (W1_enc = attn_W1[:,512:])
  k_gemm<<<dim3(64,2),256,0,stream>>>(y1, aW1+512, ab1, eproj, 8192,256,512,1024,0);
  // decoder x_t projection (+b0)
  k_gemm<<<dim3(16,16),256,0,stream>>>(tgtE, dWih0, db0, zpre, 2016,2048,128,640,0);

  k_dec_init<<<64,256,0,stream>>>(e0h[0], e0c, e1h[0], e1c, dh0[0], dc0, dh1[0], dc1);

  for (int t=0; t<TD_; t++){
    int p = t & 1;
    k_q<<<dim3(4,4),256,0,stream>>>(aT, dh1[p], q);
    k_scores<<<dim3(32,8),256,0,stream>>>(eproj, q, aW2, ab2, sc);
    k_sm_ctx<<<dim3(32,4),256,0,stream>>>(sc, y1, ctxp);
    k_lstm<<<dim3(64,4),256,0,stream>>>(ctxp, 1, zpre, 0, dTih0, dThh0,
                                        dh0[p], dc0, dh0[1-p], (float*)nullptr, t);
    k_lstm<<<dim3(64,4),256,0,stream>>>(dh0[1-p], 0, db1, 1, dTih1, dThh1,
                                        dh1[p], dc1, dh1[1-p], H1, t);
  }

  // output head: hid = relu(H1 @ out_W1^T + b1); logits = hid @ out_W2^T + b2
  k_gemm<<<dim3(16,2),256,0,stream>>>(H1, oW1, ob1, hid, 2016,256,512,512,1);
  k_gemm<<<dim3(16,250),256,0,stream>>>(hid, oW2, ob2, F, 2016,32000,256,256,2);
}

// Round 2
// 12230.598 us; speedup vs baseline: 1.0185x; 1.0185x over previous
//
#include <hip/hip_runtime.h>

// ---------------- problem constants ----------------
#define BB_ 32      // batch
#define SS_ 256     // src len
#define TT_ 64      // tgt len
#define TD_ 63      // decoder steps
#define EE_ 128     // embed
#define HH_ 256     // enc hidden per dir
#define H2_ 512     // dec hidden
#define VV_ 32000

__device__ __forceinline__ float sigf(float x){ return 1.0f/(1.0f+__expf(-x)); }
__device__ __forceinline__ float tanhf_fast(float x){ return 1.0f - 2.0f/(__expf(2.0f*x)+1.0f); }

__device__ __forceinline__ unsigned short f2bf(float f){
  unsigned u = __float_as_uint(f);
  u += 0x7fff + ((u >> 16) & 1);
  return (unsigned short)(u >> 16);
}

typedef __attribute__((ext_vector_type(8))) short short8v;
typedef __attribute__((ext_vector_type(8))) unsigned short ushort8v;
typedef __attribute__((ext_vector_type(4))) float f32x4;

// ---------------- d_out scratch layout (float offsets) ----------------
#define OFF_Z        0u           // 8192 x 2048
#define OFF_Y0       16777216u    // 8192 x 512
#define OFF_Y1       20971520u    // 8192 x 512
#define OFF_ZPRE     25165824u    // 2016 x 2048
#define OFF_H1ALL    29294592u    // 2016 x 512
#define OFF_SRCE     30326784u    // 8192 x 128
#define OFF_TGTE     31375360u    // 2016 x 128
#define OFF_EPROJ    31633408u    // 8192 x 256
#define OFF_ET0      33730560u    // 2 x 64 x 1024 x 4  (enc Whh l0 transposed)
#define OFF_ET1      34254848u
#define OFF_DTIH0    34779136u    // 128 x 2048 x 4
#define OFF_DTHH0    35827712u
#define OFF_DTIH1    36876288u
#define OFF_DTHH1    37924864u
#define OFF_AT       38973440u    // 128 x 256 x 4 (W1_dec transposed)
#define OFF_STATES   39104512u    // states, zeroed below
#define OFF_E0H0     39104512u
#define OFF_E0H1     39120896u
#define OFF_E0C      39137280u
#define OFF_E1H0     39153664u
#define OFF_E1H1     39170048u
#define OFF_E1C      39186432u
#define OFF_DH0A     39202816u
#define OFF_DH0B     39219200u
#define OFF_DC0      39235584u
#define OFF_DH1A     39251968u
#define OFF_DH1B     39268352u
#define OFF_DC1      39284736u
#define OFF_CTX      39301120u    // 32 x 512
#define N_STATES     212992u

// ---------------- utility kernels ----------------
__global__ void k_zero(float* __restrict__ p, int n){
  int i = blockIdx.x*256 + threadIdx.x;
  if (i < n) p[i] = 0.f;
}

__global__ void k_gather(const int* __restrict__ src, const int* __restrict__ tgt,
                         const float* __restrict__ emb,
                         float* __restrict__ src_e, float* __restrict__ tgt_e){
  int idx = blockIdx.x*256 + threadIdx.x;
  const int total = (8192 + 2016) * 32;
  if (idx >= total) return;
  int row = idx >> 5, j = idx & 31;
  int tok; float* dst;
  if (row < 8192){
    int s = row >> 5, b = row & 31;
    tok = src[b*SS_ + s];
    dst = src_e + (size_t)row*EE_;
  } else {
    int r2 = row - 8192;
    int t = r2 >> 5, b = r2 & 31;
    tok = tgt[b*TT_ + t];
    dst = tgt_e + (size_t)r2*EE_;
  }
  float4 v = *(const float4*)(emb + (size_t)tok*EE_ + j*4);
  *(float4*)(dst + j*4) = v;
}

// transpose W (C rows x Kd cols, row stride ldb, col offset off) into
// WT[(k/4)*C + c]*4 + (k%4)  (k-major float4 interleave)
__global__ __launch_bounds__(256) void k_transpose(
    const float* __restrict__ src, float* __restrict__ dst,
    int C, int Kd, int ldb, int off){
  __shared__ float tile[64][68];
  int c0 = blockIdx.x*64, k0 = blockIdx.y*64;
  int tid = threadIdx.x;
  for (int idx = tid; idx < 1024; idx += 256){
    int r = idx >> 4, j4 = idx & 15;
    float4 v = *(const float4*)(src + (size_t)(c0+r)*ldb + off + k0 + j4*4);
    tile[r][j4*4+0]=v.x; tile[r][j4*4+1]=v.y; tile[r][j4*4+2]=v.z; tile[r][j4*4+3]=v.w;
  }
  __syncthreads();
  for (int idx = tid; idx < 1024; idx += 256){
    int k4l = idx >> 6, cl = idx & 63;
    float4 v = make_float4(tile[cl][k4l*4+0], tile[cl][k4l*4+1],
                           tile[cl][k4l*4+2], tile[cl][k4l*4+3]);
    *(float4*)(dst + ((size_t)(k0/4 + k4l)*C + c0 + cl)*4) = v;
  }
}

// ---------------- bf16 MFMA GEMM: C = A(MxK,f32) @ B(NxK,f32)^T + bias ----------------
// B row stride ldb, col offset boff. flags: 1=relu, 2=remap (t*32+b)->(b*63+t)
// 128x128 tile, BK=64, 4 waves each 64x64 via 4x4 frags of 16x16x32 bf16.
__global__ __launch_bounds__(256) void k_mgemm(
    const float* __restrict__ A, const float* __restrict__ Bm,
    const float* __restrict__ bias, float* __restrict__ C,
    int M, int N, int K, int ldb, int boff, int flags){
  __shared__ unsigned short As[128*72];
  __shared__ unsigned short Bs[128*72];
  int tid = threadIdx.x;
  int m0 = blockIdx.x*128, n0 = blockIdx.y*128;
  int l = tid & 63, w = tid >> 6;
  int wr = w >> 1, wc = w & 1;
  int lr = l & 15, lk = (l >> 4) * 8;
  f32x4 acc[4][4];
  #pragma unroll
  for (int m=0;m<4;m++)
    #pragma unroll
    for (int n=0;n<4;n++) acc[m][n] = (f32x4){0.f,0.f,0.f,0.f};

  int r = tid >> 1, half = tid & 1;
  bool aval = (m0 + r) < M;
  const float* arow = A + (size_t)(m0 + r)*K + half*32;
  const float* brow = Bm + (size_t)(n0 + r)*ldb + boff + half*32;
  unsigned short* asd = &As[r*72 + half*32];
  unsigned short* bsd = &Bs[r*72 + half*32];

  for (int k0 = 0; k0 < K; k0 += 64){
    #pragma unroll
    for (int j = 0; j < 4; j++){
      float4 x = make_float4(0.f,0.f,0.f,0.f), y = x;
      if (aval){
        x = *(const float4*)(arow + k0 + j*8);
        y = *(const float4*)(arow + k0 + j*8 + 4);
      }
      ushort8v v;
      v[0]=f2bf(x.x); v[1]=f2bf(x.y); v[2]=f2bf(x.z); v[3]=f2bf(x.w);
      v[4]=f2bf(y.x); v[5]=f2bf(y.y); v[6]=f2bf(y.z); v[7]=f2bf(y.w);
      *(ushort8v*)(asd + j*8) = v;
      float4 p = *(const float4*)(brow + k0 + j*8);
      float4 q = *(const float4*)(brow + k0 + j*8 + 4);
      ushort8v u;
      u[0]=f2bf(p.x); u[1]=f2bf(p.y); u[2]=f2bf(p.z); u[3]=f2bf(p.w);
      u[4]=f2bf(q.x); u[5]=f2bf(q.y); u[6]=f2bf(q.z); u[7]=f2bf(q.w);
      *(ushort8v*)(bsd + j*8) = u;
    }
    __syncthreads();
    #pragma unroll
    for (int kk = 0; kk < 2; kk++){
      short8v aF[4], bF[4];
      #pragma unroll
      for (int m = 0; m < 4; m++)
        aF[m] = *(short8v*)&As[(wr*64 + m*16 + lr)*72 + kk*32 + lk];
      #pragma unroll
      for (int n = 0; n < 4; n++)
        bF[n] = *(short8v*)&Bs[(wc*64 + n*16 + lr)*72 + kk*32 + lk];
      #pragma unroll
      for (int m = 0; m < 4; m++)
        #pragma unroll
        for (int n = 0; n < 4; n++)
          acc[m][n] = __builtin_amdgcn_mfma_f32_16x16x32_bf16(aF[m], bF[n], acc[m][n], 0, 0, 0);
    }
    __syncthreads();
  }

  #pragma unroll
  for (int m = 0; m < 4; m++){
    int gr0 = m0 + wr*64 + m*16 + (l >> 4)*4;
    #pragma unroll
    for (int n = 0; n < 4; n++){
      int gc = n0 + wc*64 + n*16 + (l & 15);
      float bv = bias[gc];
      #pragma unroll
      for (int j = 0; j < 4; j++){
        int gr = gr0 + j;
        if (gr >= M) continue;
        float v = acc[m][n][j] + bv;
        if (flags & 1) v = fmaxf(v, 0.f);
        if (flags & 2){
          int t = gr >> 5, b = gr & 31;
          C[((size_t)(b*63 + t))*(size_t)N + gc] = v;
        } else {
          C[(size_t)gr*N + gc] = v;
        }
      }
    }
  }
}

// ---------------- encoder recurrent step ----------------
__global__ __launch_bounds__(256) void k_enc_step(
    const float* __restrict__ Z, const float* __restrict__ WT,
    const float* __restrict__ h_in, float* __restrict__ h_out,
    float* __restrict__ c, float* __restrict__ y, int i){
  int cs = blockIdx.x, bg = blockIdx.y, d = blockIdx.z;
  int t = d ? (SS_-1-i) : i;
  __shared__ float hs[8][256];
  __shared__ float zsl[4][16][8];
  int tid = threadIdx.x;
  for (int idx = tid; idx < 2048; idx += 256){
    int bb = idx >> 8, k = idx & 255;
    hs[bb][k] = h_in[((size_t)d*BB_ + bg*8+bb)*HH_ + k];
  }
  __syncthreads();
  int bb = tid >> 5, cl = tid & 31;
  int g0 = cl >> 4, ul = cl & 15;
  int col0 = g0*256 + cs*16 + ul;
  int col1 = (g0+2)*256 + cs*16 + ul;
  const float4* wt = (const float4*)WT + (size_t)d*65536;
  const float4* h4 = (const float4*)hs[bb];
  float a0=0.f, a1=0.f;
  #pragma unroll 8
  for (int k4=0; k4<64; k4++){
    float4 hv = h4[k4];
    float4 wa = wt[(size_t)k4*1024 + col0];
    float4 wb = wt[(size_t)k4*1024 + col1];
    a0 += wa.x*hv.x + wa.y*hv.y + wa.z*hv.z + wa.w*hv.w;
    a1 += wb.x*hv.x + wb.y*hv.y + wb.z*hv.z + wb.w*hv.w;
  }
  const float* zr = Z + ((size_t)t*BB_ + bg*8+bb)*2048 + d*1024;
  zsl[g0][ul][bb]   = zr[col0] + a0;
  zsl[g0+2][ul][bb] = zr[col1] + a1;
  __syncthreads();
  if (tid < 128){
    int u_l = tid & 15, b2 = tid >> 4;
    float zi = zsl[0][u_l][b2], zf = zsl[1][u_l][b2];
    float zg = zsl[2][u_l][b2], zo = zsl[3][u_l][b2];
    size_t ci = ((size_t)d*BB_ + bg*8+b2)*HH_ + cs*16 + u_l;
    float cn = sigf(zf)*c[ci] + sigf(zi)*tanhf_fast(zg);
    float hn = sigf(zo)*tanhf_fast(cn);
    c[ci] = cn; h_out[ci] = hn;
    y[((size_t)t*BB_ + bg*8+b2)*512 + d*256 + cs*16 + u_l] = hn;
  }
}

// ---------------- decoder LSTM step ----------------
__global__ __launch_bounds__(256) void k_lstm(
    const float* __restrict__ in1,
    const float* __restrict__ zsrc, int z_is_bias,
    const float* __restrict__ W1T, const float* __restrict__ W2T,
    const float* __restrict__ h_in, float* __restrict__ c,
    float* __restrict__ h_out, float* __restrict__ H1all, int t){
  int cs = blockIdx.x, bg = blockIdx.y, tid = threadIdx.x;
  __shared__ float s1[8][512];
  __shared__ float s2[8][512];
  __shared__ float zsl[4][8][8];
  for (int idx = tid; idx < 4096; idx += 256){
    int bb = idx >> 9, k = idx & 511;
    int b = bg*8 + bb;
    s1[bb][k] = in1[(size_t)b*512+k];
    s2[bb][k] = h_in[(size_t)b*512+k];
  }
  __syncthreads();
  int bb = tid >> 5, cl = tid & 31;
  int gate = cl >> 3, ul = cl & 7;
  int col = gate*512 + cs*8 + ul;
  const float4* w1 = (const float4*)W1T;
  const float4* w2 = (const float4*)W2T;
  const float4* p1 = (const float4*)s1[bb];
  const float4* p2 = (const float4*)s2[bb];
  float a = 0.f;
  #pragma unroll 4
  for (int k4=0; k4<128; k4++){
    float4 x = p1[k4], h = p2[k4];
    float4 wa = w1[(size_t)k4*2048 + col];
    float4 va = w2[(size_t)k4*2048 + col];
    a += wa.x*x.x + wa.y*x.y + wa.z*x.z + wa.w*x.w
       + va.x*h.x + va.y*h.y + va.z*h.z + va.w*h.w;
  }
  int b = bg*8 + bb;
  float z0 = z_is_bias ? zsrc[col] : zsrc[((size_t)t*BB_ + b)*2048 + col];
  zsl[gate][ul][bb] = z0 + a;
  __syncthreads();
  if (tid < 64){
    int u_l = tid & 7, b2 = tid >> 3;
    float zi = zsl[0][u_l][b2], zf = zsl[1][u_l][b2];
    float zg = zsl[2][u_l][b2], zo = zsl[3][u_l][b2];
    int bq = bg*8 + b2; int u = cs*8 + u_l;
    size_t ci = (size_t)bq*512 + u;
    float cn = sigf(zf)*c[ci] + sigf(zi)*tanhf_fast(zg);
    float hn = sigf(zo)*tanhf_fast(cn);
    c[ci] = cn; h_out[ci] = hn;
    if (H1all) H1all[((size_t)t*BB_ + bq)*512 + u] = hn;
  }
}

// ---------------- fused attention: q + scores + softmax + context ----------------
// grid 32 (one block per batch), block 256
__global__ __launch_bounds__(256) void k_attn(
    const float* __restrict__ aT, const float* __restrict__ h1,
    const float* __restrict__ eproj, const float* __restrict__ w2,
    const float* __restrict__ b2, const float* __restrict__ enc_out,
    float* __restrict__ ctx){
  int b = blockIdx.x, tid = threadIdx.x;
  __shared__ float hs[512];
  __shared__ float qs[256];
  __shared__ float w2s[256];
  __shared__ float red[256];
  __shared__ float as_[256];
  for (int k = tid; k < 512; k += 256) hs[k] = h1[(size_t)b*512 + k];
  w2s[tid] = w2[tid];
  __syncthreads();
  // q[tid] = dot(W1_dec[tid], h1[b])
  {
    const float4* w = (const float4*)aT;
    const float4* h4 = (const float4*)hs;
    float a0 = 0.f;
    #pragma unroll 4
    for (int k4 = 0; k4 < 128; k4++){
      float4 wa = w[(size_t)k4*256 + tid];
      float4 hv = h4[k4];
      a0 += wa.x*hv.x + wa.y*hv.y + wa.z*hv.z + wa.w*hv.w;
    }
    qs[tid] = a0;
  }
  __syncthreads();
  // scores for s = tid
  float sc;
  {
    const float4* ep = (const float4*)(eproj + ((size_t)tid*BB_ + b)*256);
    const float4* q4 = (const float4*)qs;
    const float4* w4 = (const float4*)w2s;
    float acc = 0.f;
    #pragma unroll 4
    for (int k = 0; k < 64; k++){
      float4 e = ep[k], qq = q4[k], ww = w4[k];
      acc += tanhf_fast(e.x+qq.x)*ww.x + tanhf_fast(e.y+qq.y)*ww.y
           + tanhf_fast(e.z+qq.z)*ww.z + tanhf_fast(e.w+qq.w)*ww.w;
    }
    sc = acc + b2[0];
  }
  // softmax over 256 scores
  red[tid] = sc; __syncthreads();
  for (int off = 128; off; off >>= 1){
    if (tid < off) red[tid] = fmaxf(red[tid], red[tid+off]);
    __syncthreads();
  }
  float mx = red[0]; __syncthreads();
  float ex = __expf(sc - mx);
  as_[tid] = ex; red[tid] = ex; __syncthreads();
  for (int off = 128; off; off >>= 1){
    if (tid < off) red[tid] += red[tid+off];
    __syncthreads();
  }
  float inv = 1.0f / red[0];
  // context
  float c0 = 0.f, c1 = 0.f;
  for (int s = 0; s < 256; s++){
    float a = as_[s] * inv;
    const float* eo = enc_out + ((size_t)s*BB_ + b)*512;
    c0 += a * eo[tid];
    c1 += a * eo[tid + 256];
  }
  ctx[(size_t)b*512 + tid]       = c0;
  ctx[(size_t)b*512 + tid + 256] = c1;
}

// decoder init
__global__ void k_dec_init(
    const float* __restrict__ eh0, const float* __restrict__ ec0,
    const float* __restrict__ eh1, const float* __restrict__ ec1,
    float* __restrict__ h0, float* __restrict__ c0,
    float* __restrict__ h1, float* __restrict__ c1){
  int idx = blockIdx.x*256 + threadIdx.x;
  if (idx >= BB_*512) return;
  int b = idx >> 9, u = idx & 511;
  int d = u >> 8, uu = u & 255;
  size_t s = ((size_t)d*BB_ + b)*256 + uu;
  h0[idx] = eh0[s]; c0[idx] = ec0[s];
  h1[idx] = eh1[s]; c1[idx] = ec1[s];
}

// ---------------- host launch ----------------
extern "C" void kernel_launch(void* const* d_in, const int* in_sizes, int n_in,
                              void* d_out, int out_size, void* d_ws, size_t ws_size,
                              hipStream_t stream){
  (void)in_sizes; (void)n_in; (void)out_size; (void)ws_size;
  const int*   src   = (const int*)d_in[0];
  const int*   tgt   = (const int*)d_in[1];
  const float* emb   = (const float*)d_in[2];
  const float* eWih0 = (const float*)d_in[3];
  const float* eWhh0 = (const float*)d_in[4];
  const float* eb0   = (const float*)d_in[5];
  const float* eWih1 = (const float*)d_in[6];
  const float* eWhh1 = (const float*)d_in[7];
  const float* eb1   = (const float*)d_in[8];
  const float* dWih0 = (const float*)d_in[9];
  const float* dWhh0 = (const float*)d_in[10];
  const float* db0   = (const float*)d_in[11];
  const float* dWih1 = (const float*)d_in[12];
  const float* dWhh1 = (const float*)d_in[13];
  const float* db1   = (const float*)d_in[14];
  const float* aW1   = (const float*)d_in[15];
  const float* ab1   = (const float*)d_in[16];
  const float* aW2   = (const float*)d_in[17];
  const float* ab2   = (const float*)d_in[18];
  const float* oW1   = (const float*)d_in[19];
  const float* ob1   = (const float*)d_in[20];
  const float* oW2   = (const float*)d_in[21];
  const float* ob2   = (const float*)d_in[22];

  float* F = (float*)d_out;
  float* Z     = F + OFF_Z;
  float* y0    = F + OFF_Y0;
  float* y1    = F + OFF_Y1;
  float* zpre  = F + OFF_ZPRE;
  float* H1    = F + OFF_H1ALL;
  float* srcE  = F + OFF_SRCE;
  float* tgtE  = F + OFF_TGTE;
  float* eproj = F + OFF_EPROJ;
  float* eT0   = F + OFF_ET0;
  float* eT1   = F + OFF_ET1;
  float* dTih0 = F + OFF_DTIH0;
  float* dThh0 = F + OFF_DTHH0;
  float* dTih1 = F + OFF_DTIH1;
  float* dThh1 = F + OFF_DTHH1;
  float* aT    = F + OFF_AT;
  float* e0h[2] = { F + OFF_E0H0, F + OFF_E0H1 };
  float* e0c    = F + OFF_E0C;
  float* e1h[2] = { F + OFF_E1H0, F + OFF_E1H1 };
  float* e1c    = F + OFF_E1C;
  float* dh0[2] = { F + OFF_DH0A, F + OFF_DH0B };
  float* dc0    = F + OFF_DC0;
  float* dh1[2] = { F + OFF_DH1A, F + OFF_DH1B };
  float* dc1    = F + OFF_DC1;
  float* ctx    = F + OFF_CTX;
  float* hid    = (float*)d_ws;   // 2016 x 256 (2MB)

  // weight transposes (k-major, float4-interleaved) for recurrent paths
  k_transpose<<<dim3(16,4),256,0,stream>>>(eWhh0,            eT0,          1024,256,256,0);
  k_transpose<<<dim3(16,4),256,0,stream>>>(eWhh0+1024*256,   eT0+262144,   1024,256,256,0);
  k_transpose<<<dim3(16,4),256,0,stream>>>(eWhh1,            eT1,          1024,256,256,0);
  k_transpose<<<dim3(16,4),256,0,stream>>>(eWhh1+1024*256,   eT1+262144,   1024,256,256,0);
  k_transpose<<<dim3(32,8),256,0,stream>>>(dWih0,            dTih0,        2048,512,640,128);
  k_transpose<<<dim3(32,8),256,0,stream>>>(dWhh0,            dThh0,        2048,512,512,0);
  k_transpose<<<dim3(32,8),256,0,stream>>>(dWih1,            dTih1,        2048,512,512,0);
  k_transpose<<<dim3(32,8),256,0,stream>>>(dWhh1,            dThh1,        2048,512,512,0);
  k_transpose<<<dim3(4,8),256,0,stream>>>(aW1,               aT,           256,512,1024,0);

  k_zero<<<(N_STATES+255)/256,256,0,stream>>>(F + OFF_STATES, N_STATES);
  k_gather<<<((8192+2016)*32+255)/256,256,0,stream>>>(src, tgt, emb, srcE, tgtE);

  // encoder layer0 input projection (both dirs stacked: N=2048)
  k_mgemm<<<dim3(64,16),256,0,stream>>>(srcE, eWih0, eb0, Z, 8192,2048,128, 128,0,0);
  for (int i=0;i<SS_;i++)
    k_enc_step<<<dim3(16,4,2),256,0,stream>>>(Z, eT0, e0h[i&1], e0h[1-(i&1)], e0c, y0, i);

  // encoder layer1
  k_mgemm<<<dim3(64,16),256,0,stream>>>(y0, eWih1, eb1, Z, 8192,2048,512, 512,0,0);
  for (int i=0;i<SS_;i++)
    k_enc_step<<<dim3(16,4,2),256,0,stream>>>(Z, eT1, e1h[i&1], e1h[1-(i&1)], e1c, y1, i);

  // enc_proj = enc_out @ W1_enc^T + b1   (W1_enc = attn_W1[:,512:1024])
  k_mgemm<<<dim3(64,2),256,0,stream>>>(y1, aW1, ab1, eproj, 8192,256,512, 1024,512,0);
  // decoder x_t projection (+b0): tgt_e @ dWih0[:, :128]^T
  k_mgemm<<<dim3(16,16),256,0,stream>>>(tgtE, dWih0, db0, zpre, 2016,2048,128, 640,0,0);

  k_dec_init<<<64,256,0,stream>>>(e0h[0], e0c, e1h[0], e1c, dh0[0], dc0, dh1[0], dc1);

  for (int t=0; t<TD_; t++){
    int p = t & 1;
    k_attn<<<32,256,0,stream>>>(aT, dh1[p], eproj, aW2, ab2, y1, ctx);
    k_lstm<<<dim3(64,4),256,0,stream>>>(ctx, zpre, 0, dTih0, dThh0,
                                        dh0[p], dc0, dh0[1-p], (float*)nullptr, t);
    k_lstm<<<dim3(64,4),256,0,stream>>>(dh0[1-p], db1, 1, dTih1, dThh1,
                                        dh1[p], dc1, dh1[1-p], H1, t);
  }

  // output head: hid = relu(H1 @ out_W1^T + b1); logits = hid @ out_W2^T + b2
  k_mgemm<<<dim3(16,2),256,0,stream>>>(H1, oW1, ob1, hid, 2016,256,512, 512,0,1);
  k_mgemm<<<dim3(16,250),256,0,stream>>>(hid, oW2, ob2, F, 2016,32000,256, 256,0,2);
}